// Round 15
// baseline (3448.936 us; speedup 1.0000x reference)
//
#include <hip/hip_runtime.h>
#include <hip/hip_fp16.h>

// LSTM: B=128, T=1024, H=768, C=256.
// Round 15: fewer/wider producers to attack max-of-N skew (the ~1us/step
// residual r14's ledger can't otherwise explain).
// Per XCD: 16 LSTM blocks (768thr/12 waves, 48 cols) + 8 FC blocks; grid 192.
// Per-wave work IDENTICAL to r14 (4 cols, wfrag 96 VGPR, 24 MFMA); skew pool
// 24 -> 16 producers; stage 2 chunks/thread (was 3).
// r9 spill root-cause (now explained): 65KB LDS let 2x768thr blocks/CU ->
// compiler targeted 6 waves/SIMD -> VGPR cap 85 -> wfrag spilled. Fix: LDS
// pad >80KB forces 1 block/CU -> 3 waves/SIMD -> cap 170 -> no spill.
// All sync mechanisms r10/r14-proven: flags + sc0 nt poll, wave vmcnt(0) ->
// LDS arrive -> last wave stores block flag; c deferred past flag; FC
// streams t=role+8k gated on flags>=t+2. Safe fallback = heavy barrier.

#define B_ 128
#define T_ 1024
#define H_ 768
#define C_ 256

typedef _Float16 f16;
typedef _Float16 f16x8 __attribute__((ext_vector_type(8)));
typedef float f32x4 __attribute__((ext_vector_type(4)));

#define SPIN_CAP 3000000u
#define FLAG_CAP 200000u
#define FC_CAP   3000000u

__device__ __forceinline__ float sigm_f(float x) {
  return 1.0f / (1.0f + exp2f(-1.4426950408889634f * x));
}
__device__ __forceinline__ float tanh_f(float x) {
  float ax = fabsf(x);
  float e = exp2f(-2.8853900817779268f * ax);   // e^{-2|x|}
  float t = (1.0f - e) / (1.0f + e);
  return copysignf(t, x);
}
__device__ __forceinline__ unsigned pk2(float a, float b) {
  f16 ha = (f16)a, hb = (f16)b;
  unsigned short ua = __builtin_bit_cast(unsigned short, ha);
  unsigned short ub = __builtin_bit_cast(unsigned short, hb);
  return (unsigned)ua | ((unsigned)ub << 16);
}

__global__ __launch_bounds__(768, 1) void lstm_main(
    const float* __restrict__ x,      // [128][1024]
    const float* __restrict__ w_in,   // [3072]
    const float* __restrict__ W_hh,   // [3072][768]
    const float* __restrict__ b_ih,   // [3072]
    const float* __restrict__ b_hh,   // [3072]
    const float* __restrict__ fc_b,   // [256]
    float* __restrict__ out,          // [128][1024][256]
    f16* __restrict__ hbuf,           // [2][128][768]
    const f16* __restrict__ fcWh,     // [256][768] fp16
    f16* __restrict__ c_hist,         // [1024][128][768] fp16
    unsigned* __restrict__ bar)       // [0..7]=pool [15]=reg [512+g*16(+8)]=safe [1024+g*32+j]=block flags
{
  __shared__ __align__(16) char big[49152];       // 2x 24KB h-tiles
  __shared__ __align__(16) float gbuf[12 * 320];  // per-wave 16x20 regather
  __shared__ float padlds[5632];                  // 22KB pad: total LDS >80KB -> 1 block/CU -> VGPR cap 170
  __shared__ unsigned s_arrv;
  __shared__ int s_g, s_r, s_mode, s_dead;

  const int tid = threadIdx.x;
  const int w   = tid >> 6;        // wave 0..11
  const int l   = tid & 63;
  const int bid = blockIdx.x;

  asm volatile("" :: "v"(padlds[tid & 1023]));    // keep pad alive

  // ---- registration: group = physical XCD ----
  if (tid == 0) {
    s_dead = 0;
    s_arrv = 0;
    unsigned xcc;
    asm volatile("s_getreg_b32 %0, hwreg(20, 0, 32)" : "=s"(xcc));
    xcc &= 7u;
    unsigned slot = atomicAdd(&bar[xcc], 1u);
    s_g = (int)xcc;
    s_r = (int)(slot & 31u);
    int bad = (slot >= 24u) ? 1 : 0;
    __threadfence();
    atomicAdd(&bar[15], 1u);
    unsigned it = 0;
    while (__hip_atomic_load(&bar[15], __ATOMIC_ACQUIRE, __HIP_MEMORY_SCOPE_AGENT) < 192u) {
      __builtin_amdgcn_s_sleep(2);
      if (++it > SPIN_CAP) { bad = 1; break; }
    }
    __threadfence();
#pragma unroll
    for (int i2 = 0; i2 < 8; ++i2)
      if (__hip_atomic_load(&bar[i2], __ATOMIC_RELAXED, __HIP_MEMORY_SCOPE_AGENT) != 24u) bad = 1;
    s_mode = bad;
  }
  __syncthreads();
  const int mode = s_mode;
  int g, slot;
  if (mode) { g = bid & 7; slot = bid >> 3; } else { g = s_g; slot = s_r; }
  const int isfc = (slot >= 16);
  const int role = isfc ? (slot - 16) : slot;   // LSTM: 0..15, FC: 0..7

  const int bg = g * 16;
  const int n  = l & 15;
  const int hi = l >> 4;

  unsigned* fl  = bar + 1024 + g * 32;           // 16 block flags + 16 dummy-high
  unsigned* ctr = bar + 512 + g * 16;            // safe barrier
  unsigned* gen = bar + 512 + g * 16 + 8;
  const unsigned* qp = fl + (l & 31);            // poll slot (16-31 preset high)

  if (!isfc) {
    // ======================= LSTM blocks (16/XCD) =======================
    const int J0 = role * 48;                    // 48 h-cols per block
    const int jl = n >> 2, tau = n & 3;
    const int jp_n = J0 + (w << 2) + jl;
    const float* wr = W_hh + (size_t)(tau * H_ + jp_n) * H_;

    f16x8 wfrag[24];                             // 96 VGPR, must NOT spill
#pragma unroll
    for (int ks = 0; ks < 24; ++ks) {
      const int k0 = ks * 32 + hi * 8;
      f16x8 f;
#pragma unroll
      for (int e = 0; e < 8; ++e) f[e] = (f16)wr[k0 + e];
      wfrag[ks] = f;
    }

    const int jj = hi;
    const int jp_own = J0 + (w << 2) + jj;
    float win4[4], bias4[4];
#pragma unroll
    for (int t4 = 0; t4 < 4; ++t4) {
      const int row = t4 * H_ + jp_own;
      win4[t4]  = w_in[row];
      bias4[t4] = b_ih[row] + b_hh[row];
    }
    const float* xrow = x + (size_t)(bg + n) * T_;

    float c = 0.0f;
    float* gw = gbuf + w * 320;

    if (!mode) {
      // ---------- fast ----------
      for (int t = 0; t < T_; ++t) {
        // poll all block-flags >= t; spin first 2 iters, then backoff
        unsigned it = 0;
        for (;;) {
          unsigned v;
          asm volatile("global_load_dword %0, %1, off sc0 nt\n\t"
                       "s_waitcnt vmcnt(0)"
                       : "=v"(v) : "v"(qp) : "memory");
          if (__all((int)(v >= (unsigned)t))) break;
          if (it >= 2u) __builtin_amdgcn_s_sleep(1);
          if (++it > FLAG_CAP) { s_dead = 1; break; }
        }

        // stage h_t into tile[t&1] (2 chunks/thread), XOR-swizzled
        char* tb = big + (t & 1) * 24576;
        const f16* hsrc = hbuf + (size_t)(t & 1) * (B_ * H_) + (size_t)bg * H_;
        const float* gp[2]; int ldst[2]; float4 gv4[2];
#pragma unroll
        for (int s = 0; s < 2; ++s) {
          const int ci = tid + 768 * s;
          const int bb = ci / 96, ck = ci - bb * 96;
          gp[s]   = (const float*)(hsrc + bb * H_ + ck * 8);
          ldst[s] = bb * 1536 + ((ck ^ (bb & 7)) << 4);
        }
        asm volatile(
          "global_load_dwordx4 %0, %2, off sc0 nt\n\t"
          "global_load_dwordx4 %1, %3, off sc0 nt\n\t"
          "s_waitcnt vmcnt(0)"
          : "=&v"(gv4[0]), "=&v"(gv4[1])
          : "v"(gp[0]), "v"(gp[1]) : "memory");
#pragma unroll
        for (int s = 0; s < 2; ++s) *(float4*)(tb + ldst[s]) = gv4[s];
        __syncthreads();                          // sole barrier/step
        if (s_dead) return;

        // gates = h @ W^T (2 accumulators - the schedule hipcc likes)
        f32x4 acc0 = {0.f, 0.f, 0.f, 0.f}, acc1 = {0.f, 0.f, 0.f, 0.f};
#pragma unroll
        for (int ks = 0; ks < 24; ++ks) {
          f16x8 a = *(const f16x8*)(tb + (l & 15) * 1536 +
                                    ((((ks << 2) + hi) ^ (l & 7)) << 4));
          if (ks & 1) acc1 = __builtin_amdgcn_mfma_f32_16x16x32_f16(a, wfrag[ks], acc1, 0, 0, 0);
          else        acc0 = __builtin_amdgcn_mfma_f32_16x16x32_f16(a, wfrag[ks], acc0, 0, 0, 0);
        }
        f32x4 acc = acc0 + acc1;

#pragma unroll
        for (int q = 0; q < 4; ++q)
          gw[(hi * 4 + q) * 20 + n] = acc[q];
        float4 gv = *(const float4*)(gw + n * 20 + jj * 4);  // i,f,g,o

        const float xt = xrow[t];
        const float gi = gv.x + xt * win4[0] + bias4[0];
        const float gf = gv.y + xt * win4[1] + bias4[1];
        const float gg = gv.z + xt * win4[2] + bias4[2];
        const float go = gv.w + xt * win4[3] + bias4[3];
        c = sigm_f(gf) * c + sigm_f(gi) * tanh_f(gg);
        const float h = sigm_f(go) * tanh_f(c);

        const float h1 = __shfl_down(h, 16, 64);
        const float h2 = __shfl_down(h, 32, 64);
        const float h3 = __shfl_down(h, 48, 64);
        const float c1 = __shfl_down(c, 16, 64);
        const float c2 = __shfl_down(c, 32, 64);
        const float c3 = __shfl_down(c, 48, 64);
        uint2 hp2, cp2;
        hp2.x = pk2(h, h1); hp2.y = pk2(h2, h3);
        cp2.x = pk2(c, c1); cp2.y = pk2(c2, c3);
        if (l < 16) {
          *(uint2*)(hbuf + (size_t)((t + 1) & 1) * (B_ * H_) +
                    (size_t)(bg + l) * H_ + J0 + 4 * w) = hp2;
        }
        asm volatile("s_waitcnt vmcnt(0)" ::: "memory");  // wave's h drained to L2
        if (l == 0) {
          unsigned old = atomicAdd(&s_arrv, 1u);          // LDS arrive
          if (old == 12u * (unsigned)t + 11u) {           // last wave of this step
            unsigned fv = (unsigned)(t + 1);
            asm volatile("global_store_dword %0, %1, off"
                         :: "v"(fl + role), "v"(fv) : "memory");
          }
        }
        if (l < 16) {   // deferred c: drains under next step's vmcnt; FC gates t+2
          *(uint2*)(c_hist + ((size_t)t * B_ + bg + l) * H_ + J0 + 4 * w) = cp2;
        }
      }
      // tail: certify final c-stores with flag T+1
      asm volatile("s_waitcnt vmcnt(0)" ::: "memory");
      if (l == 0) {
        unsigned old = atomicAdd(&s_arrv, 1u);
        if (old == 12u * (unsigned)T_ + 11u) {
          unsigned fv = (unsigned)(T_ + 1);
          asm volatile("global_store_dword %0, %1, off"
                       :: "v"(fl + role), "v"(fv) : "memory");
        }
      }
      return;
    } else {
      // ---------- safe (heavy 16-block acq/rel barrier) ----------
      for (int t = 0; t < T_; ++t) {
        const f16* hsrc = hbuf + (size_t)(t & 1) * (B_ * H_) + (size_t)bg * H_;
#pragma unroll
        for (int s = 0; s < 2; ++s) {
          const int ci = tid + 768 * s;
          const int bb = ci / 96, ck = ci - bb * 96;
          float4 v = *(const float4*)(hsrc + bb * H_ + ck * 8);
          *(float4*)(big + bb * 1536 + ((ck ^ (bb & 7)) << 4)) = v;
        }
        __syncthreads();

        f32x4 a0 = {0.f,0.f,0.f,0.f}, a1 = {0.f,0.f,0.f,0.f};
#pragma unroll
        for (int ks = 0; ks < 24; ++ks) {
          f16x8 a = *(const f16x8*)(big + (l & 15) * 1536 +
                                    ((((ks << 2) + hi) ^ (l & 7)) << 4));
          if (ks & 1) a1 = __builtin_amdgcn_mfma_f32_16x16x32_f16(a, wfrag[ks], a1, 0, 0, 0);
          else        a0 = __builtin_amdgcn_mfma_f32_16x16x32_f16(a, wfrag[ks], a0, 0, 0, 0);
        }
        f32x4 acc = a0 + a1;

#pragma unroll
        for (int q = 0; q < 4; ++q)
          gw[(hi * 4 + q) * 20 + n] = acc[q];
        float4 gv = *(const float4*)(gw + n * 20 + jj * 4);

        const float xt = xrow[t];
        const float gi = gv.x + xt * win4[0] + bias4[0];
        const float gf = gv.y + xt * win4[1] + bias4[1];
        const float gg = gv.z + xt * win4[2] + bias4[2];
        const float go = gv.w + xt * win4[3] + bias4[3];
        c = sigm_f(gf) * c + sigm_f(gi) * tanh_f(gg);
        const float h = sigm_f(go) * tanh_f(c);

        hbuf[(size_t)((t + 1) & 1) * (B_ * H_) + (size_t)(bg + n) * H_ + jp_own] = (f16)h;
        c_hist[((size_t)t * B_ + bg + n) * H_ + jp_own] = (f16)c;

        __syncthreads();
        if (tid == 0) {
          __threadfence();
          unsigned g0 = __hip_atomic_load(gen, __ATOMIC_ACQUIRE, __HIP_MEMORY_SCOPE_AGENT);
          unsigned a  = __hip_atomic_fetch_add(ctr, 1u, __ATOMIC_ACQ_REL, __HIP_MEMORY_SCOPE_AGENT);
          if (a == 15u) {
            __hip_atomic_store(ctr, 0u, __ATOMIC_RELAXED, __HIP_MEMORY_SCOPE_AGENT);
            __hip_atomic_fetch_add(gen, 1u, __ATOMIC_RELEASE, __HIP_MEMORY_SCOPE_AGENT);
          } else {
            unsigned it = 0;
            while (__hip_atomic_load(gen, __ATOMIC_ACQUIRE, __HIP_MEMORY_SCOPE_AGENT) == g0) {
              __builtin_amdgcn_s_sleep(1);
              if (++it > SPIN_CAP) { s_dead = 1; break; }
            }
          }
          __threadfence();
        }
        __syncthreads();
        if (s_dead) return;
      }
      return;
    }
  }

  // ======================= FC blocks (8/XCD) =======================
  if (!mode) {
    for (int k = 0; k < 128; ++k) {
      const int t = role + (k << 3);
      const unsigned need = (unsigned)(t + 2);
      unsigned it = 0;
      for (;;) {
        unsigned v;
        asm volatile("global_load_dword %0, %1, off sc0 nt\n\t"
                     "s_waitcnt vmcnt(0)"
                     : "=v"(v) : "v"(qp) : "memory");
        if (__all((int)(v >= need))) break;
        __builtin_amdgcn_s_sleep(32);             // lazy: FC has huge slack
        if (++it > FC_CAP) return;
      }

      const f16* ar = c_hist + ((size_t)t * B_ + bg + n) * H_;
      const f16* ab = ar + hi * 8;
      f16x8 afrag[24];
#pragma unroll
      for (int kg = 0; kg < 3; ++kg) {
        asm volatile(
          "global_load_dwordx4 %0, %8, off sc0 nt\n\t"
          "global_load_dwordx4 %1, %8, off offset:64 sc0 nt\n\t"
          "global_load_dwordx4 %2, %8, off offset:128 sc0 nt\n\t"
          "global_load_dwordx4 %3, %8, off offset:192 sc0 nt\n\t"
          "global_load_dwordx4 %4, %8, off offset:256 sc0 nt\n\t"
          "global_load_dwordx4 %5, %8, off offset:320 sc0 nt\n\t"
          "global_load_dwordx4 %6, %8, off offset:384 sc0 nt\n\t"
          "global_load_dwordx4 %7, %8, off offset:448 sc0 nt\n\t"
          "s_waitcnt vmcnt(0)"
          : "=&v"(afrag[kg * 8 + 0]), "=&v"(afrag[kg * 8 + 1]),
            "=&v"(afrag[kg * 8 + 2]), "=&v"(afrag[kg * 8 + 3]),
            "=&v"(afrag[kg * 8 + 4]), "=&v"(afrag[kg * 8 + 5]),
            "=&v"(afrag[kg * 8 + 6]), "=&v"(afrag[kg * 8 + 7])
          : "v"(ab + kg * 256)
          : "memory");
      }
      for (int nt2 = w; nt2 < 16; nt2 += 12) {
        const f16* br = fcWh + (size_t)(nt2 * 16 + n) * H_ + hi * 8;
        f32x4 fa = {0.f, 0.f, 0.f, 0.f};
#pragma unroll
        for (int ks = 0; ks < 24; ++ks) {
          f16x8 bfr = *(const f16x8*)(br + ks * 32);   // plain: L1/L2-cached
          fa = __builtin_amdgcn_mfma_f32_16x16x32_f16(afrag[ks], bfr, fa, 0, 0, 0);
        }
        const float fb = fc_b[nt2 * 16 + n];
        float* ob = out + (size_t)t * C_ + nt2 * 16 + n;
#pragma unroll
        for (int q = 0; q < 4; ++q)
          ob[(size_t)(bg + hi * 4 + q) * ((size_t)T_ * C_)] = fa[q] + fb;
      }
    }
  } else {
    // safe: wait for whole recurrence, then plain loads
    if (tid == 0) {
      unsigned it = 0;
      while (__hip_atomic_load(gen, __ATOMIC_ACQUIRE, __HIP_MEMORY_SCOPE_AGENT) < (unsigned)T_) {
        __builtin_amdgcn_s_sleep(8);
        if (++it > SPIN_CAP) { s_dead = 1; break; }
      }
    }
    __syncthreads();
    if (s_dead) return;
    for (int k = 0; k < 128; ++k) {
      const int t = role + (k << 3);
      const f16* ar = c_hist + ((size_t)t * B_ + bg + n) * H_;
      f16x8 afrag[24];
#pragma unroll
      for (int ks = 0; ks < 24; ++ks)
        afrag[ks] = *(const f16x8*)(ar + ks * 32 + hi * 8);
      for (int nt2 = w; nt2 < 16; nt2 += 12) {
        const f16* br = fcWh + (size_t)(nt2 * 16 + n) * H_ + hi * 8;
        f32x4 fa = {0.f, 0.f, 0.f, 0.f};
#pragma unroll
        for (int ks = 0; ks < 24; ++ks) {
          f16x8 bfr = *(const f16x8*)(br + ks * 32);
          fa = __builtin_amdgcn_mfma_f32_16x16x32_f16(afrag[ks], bfr, fa, 0, 0, 0);
        }
        const float fb = fc_b[nt2 * 16 + n];
        float* ob = out + (size_t)t * C_ + nt2 * 16 + n;
#pragma unroll
        for (int q = 0; q < 4; ++q)
          ob[(size_t)(bg + hi * 4 + q) * ((size_t)T_ * C_)] = fa[q] + fb;
      }
    }
  }
}

__global__ __launch_bounds__(256) void prep(
    const float* __restrict__ fcW, f16* __restrict__ fcWh,
    f16* __restrict__ hbuf, unsigned* __restrict__ bar)
{
  const int i = blockIdx.x * 256 + threadIdx.x;
  const int nth = gridDim.x * 256;
  for (int k = i; k < C_ * H_; k += nth) fcWh[k] = (f16)fcW[k];
  for (int k = i; k < 2 * B_ * H_; k += nth) hbuf[k] = (f16)0.0f;
  if (i < 1024) bar[i] = 0u;
  else if (i < 1280) {                    // flags: 16 real (0) + 16 dummy (high)
    const int j = (i - 1024) & 31;
    bar[i] = (j < 16) ? 0u : 0x7fffffffu;
  }
}

extern "C" void kernel_launch(void* const* d_in, const int* in_sizes, int n_in,
                              void* d_out, int out_size, void* d_ws, size_t ws_size,
                              hipStream_t stream) {
  const float* x   = (const float*)d_in[0];
  const float* Wih = (const float*)d_in[1];
  const float* Whh = (const float*)d_in[2];
  const float* bih = (const float*)d_in[3];
  const float* bhh = (const float*)d_in[4];
  const float* fcW = (const float*)d_in[5];
  const float* fcb = (const float*)d_in[6];
  float* out = (float*)d_out;

  char* ws = (char*)d_ws;
  f16* hbuf      = (f16*)ws;                   // 393216 B
  f16* fcWh      = (f16*)(ws + 393216);        // 393216 B
  unsigned* bar  = (unsigned*)(ws + 786432);   // 16384 B
  f16* c_hist    = (f16*)(ws + (1 << 20));     // 201326592 B
  const size_t need = (size_t)(1 << 20) + 201326592ull;
  if (ws_size < need) {
    hipMemsetAsync(d_out, 0, (size_t)out_size * 4, stream);
    return;
  }

  hipLaunchKernelGGL(prep, dim3(256), dim3(256), 0, stream, fcW, fcWh, hbuf, bar);

  void* args[] = { (void*)&x, (void*)&Wih, (void*)&Whh, (void*)&bih, (void*)&bhh,
                   (void*)&fcb, (void*)&out, (void*)&hbuf, (void*)&fcWh,
                   (void*)&c_hist, (void*)&bar };
  hipLaunchCooperativeKernel((void*)lstm_main, dim3(192), dim3(768), args, 0, stream);
}

// Round 16
// 2308.110 us; speedup vs baseline: 1.4943x; 1.4943x over previous
//
#include <hip/hip_runtime.h>
#include <hip/hip_fp16.h>

// LSTM: B=128, T=1024, H=768, C=256.
// FINAL (round 16) = exact r14, the proven best (2310us).
// Ledger of the session:
//  r1  31.2ms  acq/rel agent barrier -> L2 writeback storm (WRITE 1.13GB)
//  r3   2.87ms relaxed sc1 MALL barrier (no cache maintenance)
//  r5/r7 flags: plain store -> same-XCD sc0 nt load proven coherent; sc0
//        without nt spins on stale L1 (r4/r6 dead) - nt is load-bearing.
//  r10  2.32ms 24 LSTM(512thr)+8 FC blocks/XCD, 1 barrier/step, FC overlap
//        (FETCH 827->137MB), no spill (VGPR 116).
//  r11-r15 probes: pipelined poll (reg-lifetime crash; then neutral),
//        4-acc MFMA + epilogue reorder (-150us REGRESSION - hipcc's 2-acc
//        schedule is better), flag padding (neutral), 768-thr wide blocks
//        (VGPR caps at 84 -> wfrag spills -> 3.4ms; LDS-pad DCE'd twice).
// Remaining limiter: serialized per-step chain (ACK -> flag -> poll ->
// stage -> barrier -> MFMA/pointwise) x 1024; latency-bound (MfmaUtil 11%,
// HBM 2.4%), not a resource roofline.

#define B_ 128
#define T_ 1024
#define H_ 768
#define C_ 256

typedef _Float16 f16;
typedef _Float16 f16x8 __attribute__((ext_vector_type(8)));
typedef float f32x4 __attribute__((ext_vector_type(4)));

#define SPIN_CAP 3000000u
#define FLAG_CAP 200000u
#define FC_CAP   3000000u

__device__ __forceinline__ float sigm_f(float x) {
  return 1.0f / (1.0f + exp2f(-1.4426950408889634f * x));
}
__device__ __forceinline__ float tanh_f(float x) {
  float ax = fabsf(x);
  float e = exp2f(-2.8853900817779268f * ax);   // e^{-2|x|}
  float t = (1.0f - e) / (1.0f + e);
  return copysignf(t, x);
}
__device__ __forceinline__ unsigned pk2(float a, float b) {
  f16 ha = (f16)a, hb = (f16)b;
  unsigned short ua = __builtin_bit_cast(unsigned short, ha);
  unsigned short ub = __builtin_bit_cast(unsigned short, hb);
  return (unsigned)ua | ((unsigned)ub << 16);
}

__global__ __launch_bounds__(512, 2) void lstm_main(
    const float* __restrict__ x,      // [128][1024]
    const float* __restrict__ w_in,   // [3072]
    const float* __restrict__ W_hh,   // [3072][768]
    const float* __restrict__ b_ih,   // [3072]
    const float* __restrict__ b_hh,   // [3072]
    const float* __restrict__ fc_b,   // [256]
    float* __restrict__ out,          // [128][1024][256]
    f16* __restrict__ hbuf,           // [2][128][768]
    const f16* __restrict__ fcWh,     // [256][768] fp16
    f16* __restrict__ c_hist,         // [1024][128][768] fp16
    unsigned* __restrict__ bar)       // [0..7]=pool [15]=reg [512+g*16(+8)]=safe [1024+g*32+j]=block flags
{
  __shared__ __align__(16) char big[49152];      // 2x 24KB h-tiles
  __shared__ __align__(16) float gbuf[8 * 320];  // per-wave 16x20 regather
  __shared__ unsigned s_arrv;
  __shared__ int s_g, s_r, s_mode, s_dead;

  const int tid = threadIdx.x;
  const int w   = tid >> 6;        // wave 0..7
  const int l   = tid & 63;
  const int bid = blockIdx.x;

  // ---- registration: group = physical XCD ----
  if (tid == 0) {
    s_dead = 0;
    s_arrv = 0;
    unsigned xcc;
    asm volatile("s_getreg_b32 %0, hwreg(20, 0, 32)" : "=s"(xcc));
    xcc &= 7u;
    unsigned slot = atomicAdd(&bar[xcc], 1u);
    s_g = (int)xcc;
    s_r = (int)(slot & 31u);
    int bad = (slot >= 32u) ? 1 : 0;
    __threadfence();
    atomicAdd(&bar[15], 1u);
    unsigned it = 0;
    while (__hip_atomic_load(&bar[15], __ATOMIC_ACQUIRE, __HIP_MEMORY_SCOPE_AGENT) < 256u) {
      __builtin_amdgcn_s_sleep(2);
      if (++it > SPIN_CAP) { bad = 1; break; }
    }
    __threadfence();
#pragma unroll
    for (int i2 = 0; i2 < 8; ++i2)
      if (__hip_atomic_load(&bar[i2], __ATOMIC_RELAXED, __HIP_MEMORY_SCOPE_AGENT) != 32u) bad = 1;
    s_mode = bad;
  }
  __syncthreads();
  const int mode = s_mode;
  int g, slot;
  if (mode) { g = bid & 7; slot = bid >> 3; } else { g = s_g; slot = s_r; }
  const int isfc = (slot >= 24);
  const int role = isfc ? (slot - 24) : slot;   // LSTM: 0..23, FC: 0..7

  const int bg = g * 16;
  const int n  = l & 15;
  const int hi = l >> 4;

  unsigned* fl  = bar + 1024 + g * 32;           // 24 block flags + 8 dummy-high
  unsigned* ctr = bar + 512 + g * 16;            // safe barrier
  unsigned* gen = bar + 512 + g * 16 + 8;
  const unsigned* qp = fl + (l & 31);            // poll slot (dummies preset high)

  if (!isfc) {
    // ======================= LSTM blocks (24/XCD) =======================
    const int J0 = role * 32;                    // 32 h-cols per block
    const int jl = n >> 2, tau = n & 3;
    const int jp_n = J0 + (w << 2) + jl;
    const float* wr = W_hh + (size_t)(tau * H_ + jp_n) * H_;

    f16x8 wfrag[24];                             // 96 VGPR, must NOT spill
#pragma unroll
    for (int ks = 0; ks < 24; ++ks) {
      const int k0 = ks * 32 + hi * 8;
      f16x8 f;
#pragma unroll
      for (int e = 0; e < 8; ++e) f[e] = (f16)wr[k0 + e];
      wfrag[ks] = f;
    }

    const int jj = hi;
    const int jp_own = J0 + (w << 2) + jj;
    float win4[4], bias4[4];
#pragma unroll
    for (int t4 = 0; t4 < 4; ++t4) {
      const int row = t4 * H_ + jp_own;
      win4[t4]  = w_in[row];
      bias4[t4] = b_ih[row] + b_hh[row];
    }
    const float* xrow = x + (size_t)(bg + n) * T_;

    float c = 0.0f;
    float* gw = gbuf + w * 320;

    if (!mode) {
      // ---------- fast ----------
      for (int t = 0; t < T_; ++t) {
        // poll all block-flags >= t; spin first 2 iters, then backoff
        unsigned it = 0;
        for (;;) {
          unsigned v;
          asm volatile("global_load_dword %0, %1, off sc0 nt\n\t"
                       "s_waitcnt vmcnt(0)"
                       : "=v"(v) : "v"(qp) : "memory");
          if (__all((int)(v >= (unsigned)t))) break;
          if (it >= 2u) __builtin_amdgcn_s_sleep(1);
          if (++it > FLAG_CAP) { s_dead = 1; break; }
        }

        // stage h_t into tile[t&1] (3 chunks/thread), XOR-swizzled
        char* tb = big + (t & 1) * 24576;
        const f16* hsrc = hbuf + (size_t)(t & 1) * (B_ * H_) + (size_t)bg * H_;
        const float* gp[3]; int ldst[3]; float4 gv4[3];
#pragma unroll
        for (int s = 0; s < 3; ++s) {
          const int ci = tid + 512 * s;
          const int bb = ci / 96, ck = ci - bb * 96;
          gp[s]   = (const float*)(hsrc + bb * H_ + ck * 8);
          ldst[s] = bb * 1536 + ((ck ^ (bb & 7)) << 4);
        }
        asm volatile(
          "global_load_dwordx4 %0, %3, off sc0 nt\n\t"
          "global_load_dwordx4 %1, %4, off sc0 nt\n\t"
          "global_load_dwordx4 %2, %5, off sc0 nt\n\t"
          "s_waitcnt vmcnt(0)"
          : "=&v"(gv4[0]), "=&v"(gv4[1]), "=&v"(gv4[2])
          : "v"(gp[0]), "v"(gp[1]), "v"(gp[2]) : "memory");
#pragma unroll
        for (int s = 0; s < 3; ++s) *(float4*)(tb + ldst[s]) = gv4[s];
        __syncthreads();                          // sole barrier/step
        if (s_dead) return;

        // gates = h @ W^T (2 accumulators - the schedule hipcc likes)
        f32x4 acc0 = {0.f, 0.f, 0.f, 0.f}, acc1 = {0.f, 0.f, 0.f, 0.f};
#pragma unroll
        for (int ks = 0; ks < 24; ++ks) {
          f16x8 a = *(const f16x8*)(tb + (l & 15) * 1536 +
                                    ((((ks << 2) + hi) ^ (l & 7)) << 4));
          if (ks & 1) acc1 = __builtin_amdgcn_mfma_f32_16x16x32_f16(a, wfrag[ks], acc1, 0, 0, 0);
          else        acc0 = __builtin_amdgcn_mfma_f32_16x16x32_f16(a, wfrag[ks], acc0, 0, 0, 0);
        }
        f32x4 acc = acc0 + acc1;

#pragma unroll
        for (int q = 0; q < 4; ++q)
          gw[(hi * 4 + q) * 20 + n] = acc[q];
        float4 gv = *(const float4*)(gw + n * 20 + jj * 4);  // i,f,g,o

        const float xt = xrow[t];
        const float gi = gv.x + xt * win4[0] + bias4[0];
        const float gf = gv.y + xt * win4[1] + bias4[1];
        const float gg = gv.z + xt * win4[2] + bias4[2];
        const float go = gv.w + xt * win4[3] + bias4[3];
        c = sigm_f(gf) * c + sigm_f(gi) * tanh_f(gg);
        const float h = sigm_f(go) * tanh_f(c);

        const float h1 = __shfl_down(h, 16, 64);
        const float h2 = __shfl_down(h, 32, 64);
        const float h3 = __shfl_down(h, 48, 64);
        const float c1 = __shfl_down(c, 16, 64);
        const float c2 = __shfl_down(c, 32, 64);
        const float c3 = __shfl_down(c, 48, 64);
        uint2 hp2, cp2;
        hp2.x = pk2(h, h1); hp2.y = pk2(h2, h3);
        cp2.x = pk2(c, c1); cp2.y = pk2(c2, c3);
        if (l < 16) {
          *(uint2*)(hbuf + (size_t)((t + 1) & 1) * (B_ * H_) +
                    (size_t)(bg + l) * H_ + J0 + 4 * w) = hp2;
        }
        asm volatile("s_waitcnt vmcnt(0)" ::: "memory");  // wave's h drained to L2
        if (l == 0) {
          unsigned old = atomicAdd(&s_arrv, 1u);          // LDS arrive
          if (old == 8u * (unsigned)t + 7u) {             // 8th wave of this step
            unsigned fv = (unsigned)(t + 1);
            asm volatile("global_store_dword %0, %1, off"
                         :: "v"(fl + role), "v"(fv) : "memory");
          }
        }
        if (l < 16) {   // deferred c: drains under next step's vmcnt; FC gates t+2
          *(uint2*)(c_hist + ((size_t)t * B_ + bg + l) * H_ + J0 + 4 * w) = cp2;
        }
      }
      // tail: certify final c-stores with flag T+1
      asm volatile("s_waitcnt vmcnt(0)" ::: "memory");
      if (l == 0) {
        unsigned old = atomicAdd(&s_arrv, 1u);
        if (old == 8u * (unsigned)T_ + 7u) {
          unsigned fv = (unsigned)(T_ + 1);
          asm volatile("global_store_dword %0, %1, off"
                       :: "v"(fl + role), "v"(fv) : "memory");
        }
      }
      return;
    } else {
      // ---------- safe (heavy 24-block acq/rel barrier) ----------
      for (int t = 0; t < T_; ++t) {
        const f16* hsrc = hbuf + (size_t)(t & 1) * (B_ * H_) + (size_t)bg * H_;
#pragma unroll
        for (int s = 0; s < 3; ++s) {
          const int ci = tid + 512 * s;
          const int bb = ci / 96, ck = ci - bb * 96;
          float4 v = *(const float4*)(hsrc + bb * H_ + ck * 8);
          *(float4*)(big + bb * 1536 + ((ck ^ (bb & 7)) << 4)) = v;
        }
        __syncthreads();

        f32x4 a0 = {0.f,0.f,0.f,0.f}, a1 = {0.f,0.f,0.f,0.f};
#pragma unroll
        for (int ks = 0; ks < 24; ++ks) {
          f16x8 a = *(const f16x8*)(big + (l & 15) * 1536 +
                                    ((((ks << 2) + hi) ^ (l & 7)) << 4));
          if (ks & 1) a1 = __builtin_amdgcn_mfma_f32_16x16x32_f16(a, wfrag[ks], a1, 0, 0, 0);
          else        a0 = __builtin_amdgcn_mfma_f32_16x16x32_f16(a, wfrag[ks], a0, 0, 0, 0);
        }
        f32x4 acc = a0 + a1;

#pragma unroll
        for (int q = 0; q < 4; ++q)
          gw[(hi * 4 + q) * 20 + n] = acc[q];
        float4 gv = *(const float4*)(gw + n * 20 + jj * 4);

        const float xt = xrow[t];
        const float gi = gv.x + xt * win4[0] + bias4[0];
        const float gf = gv.y + xt * win4[1] + bias4[1];
        const float gg = gv.z + xt * win4[2] + bias4[2];
        const float go = gv.w + xt * win4[3] + bias4[3];
        c = sigm_f(gf) * c + sigm_f(gi) * tanh_f(gg);
        const float h = sigm_f(go) * tanh_f(c);

        hbuf[(size_t)((t + 1) & 1) * (B_ * H_) + (size_t)(bg + n) * H_ + jp_own] = (f16)h;
        c_hist[((size_t)t * B_ + bg + n) * H_ + jp_own] = (f16)c;

        __syncthreads();
        if (tid == 0) {
          __threadfence();
          unsigned g0 = __hip_atomic_load(gen, __ATOMIC_ACQUIRE, __HIP_MEMORY_SCOPE_AGENT);
          unsigned a  = __hip_atomic_fetch_add(ctr, 1u, __ATOMIC_ACQ_REL, __HIP_MEMORY_SCOPE_AGENT);
          if (a == 23u) {
            __hip_atomic_store(ctr, 0u, __ATOMIC_RELAXED, __HIP_MEMORY_SCOPE_AGENT);
            __hip_atomic_fetch_add(gen, 1u, __ATOMIC_RELEASE, __HIP_MEMORY_SCOPE_AGENT);
          } else {
            unsigned it = 0;
            while (__hip_atomic_load(gen, __ATOMIC_ACQUIRE, __HIP_MEMORY_SCOPE_AGENT) == g0) {
              __builtin_amdgcn_s_sleep(1);
              if (++it > SPIN_CAP) { s_dead = 1; break; }
            }
          }
          __threadfence();
        }
        __syncthreads();
        if (s_dead) return;
      }
      return;
    }
  }

  // ======================= FC blocks (8/XCD) =======================
  if (!mode) {
    for (int k = 0; k < 128; ++k) {
      const int t = role + (k << 3);
      const unsigned need = (unsigned)(t + 2);
      unsigned it = 0;
      for (;;) {
        unsigned v;
        asm volatile("global_load_dword %0, %1, off sc0 nt\n\t"
                     "s_waitcnt vmcnt(0)"
                     : "=v"(v) : "v"(qp) : "memory");
        if (__all((int)(v >= need))) break;
        __builtin_amdgcn_s_sleep(32);             // lazy: FC has huge slack
        if (++it > FC_CAP) return;
      }

      const f16* ar = c_hist + ((size_t)t * B_ + bg + n) * H_;
      const f16* ab = ar + hi * 8;
      f16x8 afrag[24];
#pragma unroll
      for (int kg = 0; kg < 3; ++kg) {
        asm volatile(
          "global_load_dwordx4 %0, %8, off sc0 nt\n\t"
          "global_load_dwordx4 %1, %8, off offset:64 sc0 nt\n\t"
          "global_load_dwordx4 %2, %8, off offset:128 sc0 nt\n\t"
          "global_load_dwordx4 %3, %8, off offset:192 sc0 nt\n\t"
          "global_load_dwordx4 %4, %8, off offset:256 sc0 nt\n\t"
          "global_load_dwordx4 %5, %8, off offset:320 sc0 nt\n\t"
          "global_load_dwordx4 %6, %8, off offset:384 sc0 nt\n\t"
          "global_load_dwordx4 %7, %8, off offset:448 sc0 nt\n\t"
          "s_waitcnt vmcnt(0)"
          : "=&v"(afrag[kg * 8 + 0]), "=&v"(afrag[kg * 8 + 1]),
            "=&v"(afrag[kg * 8 + 2]), "=&v"(afrag[kg * 8 + 3]),
            "=&v"(afrag[kg * 8 + 4]), "=&v"(afrag[kg * 8 + 5]),
            "=&v"(afrag[kg * 8 + 6]), "=&v"(afrag[kg * 8 + 7])
          : "v"(ab + kg * 256)
          : "memory");
      }
#pragma unroll
      for (int q2 = 0; q2 < 2; ++q2) {
        const int nt2 = w + q2 * 8;
        const f16* br = fcWh + (size_t)(nt2 * 16 + n) * H_ + hi * 8;
        f32x4 fa = {0.f, 0.f, 0.f, 0.f};
#pragma unroll
        for (int ks = 0; ks < 24; ++ks) {
          f16x8 bfr = *(const f16x8*)(br + ks * 32);   // plain: L1/L2-cached
          fa = __builtin_amdgcn_mfma_f32_16x16x32_f16(afrag[ks], bfr, fa, 0, 0, 0);
        }
        const float fb = fc_b[nt2 * 16 + n];
        float* ob = out + (size_t)t * C_ + nt2 * 16 + n;
#pragma unroll
        for (int q = 0; q < 4; ++q)
          ob[(size_t)(bg + hi * 4 + q) * ((size_t)T_ * C_)] = fa[q] + fb;
      }
    }
  } else {
    // safe: wait for whole recurrence, then plain loads
    if (tid == 0) {
      unsigned it = 0;
      while (__hip_atomic_load(gen, __ATOMIC_ACQUIRE, __HIP_MEMORY_SCOPE_AGENT) < (unsigned)T_) {
        __builtin_amdgcn_s_sleep(8);
        if (++it > SPIN_CAP) { s_dead = 1; break; }
      }
    }
    __syncthreads();
    if (s_dead) return;
    for (int k = 0; k < 128; ++k) {
      const int t = role + (k << 3);
      const f16* ar = c_hist + ((size_t)t * B_ + bg + n) * H_;
      f16x8 afrag[24];
#pragma unroll
      for (int ks = 0; ks < 24; ++ks)
        afrag[ks] = *(const f16x8*)(ar + ks * 32 + hi * 8);
#pragma unroll
      for (int q2 = 0; q2 < 2; ++q2) {
        const int nt2 = w + q2 * 8;
        const f16* br = fcWh + (size_t)(nt2 * 16 + n) * H_ + hi * 8;
        f32x4 fa = {0.f, 0.f, 0.f, 0.f};
#pragma unroll
        for (int ks = 0; ks < 24; ++ks) {
          f16x8 bfr = *(const f16x8*)(br + ks * 32);
          fa = __builtin_amdgcn_mfma_f32_16x16x32_f16(afrag[ks], bfr, fa, 0, 0, 0);
        }
        const float fb = fc_b[nt2 * 16 + n];
        float* ob = out + (size_t)t * C_ + nt2 * 16 + n;
#pragma unroll
        for (int q = 0; q < 4; ++q)
          ob[(size_t)(bg + hi * 4 + q) * ((size_t)T_ * C_)] = fa[q] + fb;
      }
    }
  }
}

__global__ __launch_bounds__(256) void prep(
    const float* __restrict__ fcW, f16* __restrict__ fcWh,
    f16* __restrict__ hbuf, unsigned* __restrict__ bar)
{
  const int i = blockIdx.x * 256 + threadIdx.x;
  const int nth = gridDim.x * 256;
  for (int k = i; k < C_ * H_; k += nth) fcWh[k] = (f16)fcW[k];
  for (int k = i; k < 2 * B_ * H_; k += nth) hbuf[k] = (f16)0.0f;
  if (i < 1024) bar[i] = 0u;
  else if (i < 1280) {                    // flags: 24 real (0) + 8 dummy (high)
    const int j = (i - 1024) & 31;
    bar[i] = (j < 24) ? 0u : 0x7fffffffu;
  }
}

extern "C" void kernel_launch(void* const* d_in, const int* in_sizes, int n_in,
                              void* d_out, int out_size, void* d_ws, size_t ws_size,
                              hipStream_t stream) {
  const float* x   = (const float*)d_in[0];
  const float* Wih = (const float*)d_in[1];
  const float* Whh = (const float*)d_in[2];
  const float* bih = (const float*)d_in[3];
  const float* bhh = (const float*)d_in[4];
  const float* fcW = (const float*)d_in[5];
  const float* fcb = (const float*)d_in[6];
  float* out = (float*)d_out;

  char* ws = (char*)d_ws;
  f16* hbuf      = (f16*)ws;                   // 393216 B
  f16* fcWh      = (f16*)(ws + 393216);        // 393216 B
  unsigned* bar  = (unsigned*)(ws + 786432);   // 16384 B
  f16* c_hist    = (f16*)(ws + (1 << 20));     // 201326592 B
  const size_t need = (size_t)(1 << 20) + 201326592ull;
  if (ws_size < need) {
    hipMemsetAsync(d_out, 0, (size_t)out_size * 4, stream);
    return;
  }

  hipLaunchKernelGGL(prep, dim3(256), dim3(256), 0, stream, fcW, fcWh, hbuf, bar);

  void* args[] = { (void*)&x, (void*)&Wih, (void*)&Whh, (void*)&bih, (void*)&bhh,
                   (void*)&fcb, (void*)&out, (void*)&hbuf, (void*)&fcWh,
                   (void*)&c_hist, (void*)&bar };
  hipLaunchCooperativeKernel((void*)lstm_main, dim3(256), dim3(512), args, 0, stream);
}